// Round 13
// baseline (354.380 us; speedup 1.0000x reference)
//
#include <hip/hip_runtime.h>
#include <hip/hip_bf16.h>
#include <math.h>

#define DEV __device__ __forceinline__

typedef __attribute__((ext_vector_type(8))) short bf16x8;
typedef __attribute__((ext_vector_type(4))) float f32x4;

static DEV float softplus_f(float x){ return fmaxf(x,0.f) + log1pf(expf(-fabsf(x))); }
static DEV float logsig_f(float x){ return fminf(x,0.f) - log1pf(expf(-fabsf(x))); }
static DEV float silu_f(float x){ return x / (1.f + expf(-x)); }
static DEV unsigned short f2bf(float f){
  union { float f; unsigned u; } v; v.f = f;
  unsigned r = (v.u + 0x7fffu + ((v.u >> 16) & 1u)) >> 16;
  return (unsigned short)r;
}
static DEV float bf2f(unsigned short u){
  union { unsigned u; float f; } v; v.u = ((unsigned)u) << 16; return v.f;
}
static DEV void load_lds16(const unsigned short* g, unsigned short* lds){
  __builtin_amdgcn_global_load_lds(
      (const __attribute__((address_space(1))) void*)g,
      (__attribute__((address_space(3))) void*)lds, 16, 0, 0);
}

// ---------------- weight prep: 960 transpose tiles (64m x 128k) + 256 compose blocks ----------------
__global__ __launch_bounds__(256) void wprep(
    const float* __restrict__ Wp, const float* __restrict__ Wq,
    const float* __restrict__ Wk, const float* __restrict__ Wv,
    const float* __restrict__ Wd, const float* __restrict__ Wi,
    const float* __restrict__ Wf,
    unsigned short* projT0, unsigned short* projT1,
    unsigned short* qT0, unsigned short* kT0, unsigned short* kT1,
    unsigned short* vT0, unsigned short* vT1, unsigned short* dT0,
    float* __restrict__ Wc, unsigned* __restrict__ cnts)
{
  int bid = blockIdx.x;
  if (bid == 0 && threadIdx.x < 40) cnts[threadIdx.x] = 0;
  if (bid >= 960){
    int fb = bid - 960;                       // 0..255
    int gid = fb * 4 + (threadIdx.x >> 6);    // 0..1023
    int l = gid >> 9, d = gid & 511;
    int lane = threadIdx.x & 63;
    const float* wp = Wp + (size_t)l*512*2048 + (size_t)d*2048 + lane*16;
    const float* wi = Wi + (size_t)l*1024*8;
    const float* wf = Wf + (size_t)l*1024*8;
    float acc[16];
    #pragma unroll
    for (int q = 0; q < 16; ++q) acc[q] = 0.f;
    #pragma unroll 4
    for (int u = 0; u < 16; ++u){
      float xv = wp[u];
      int j = lane*16 + u;
      float4 wi0 = *(const float4*)(wi + j*8);
      float4 wi1 = *(const float4*)(wi + j*8 + 4);
      float4 wf0 = *(const float4*)(wf + j*8);
      float4 wf1 = *(const float4*)(wf + j*8 + 4);
      acc[0]  = fmaf(xv, wi0.x, acc[0]);  acc[1]  = fmaf(xv, wi0.y, acc[1]);
      acc[2]  = fmaf(xv, wi0.z, acc[2]);  acc[3]  = fmaf(xv, wi0.w, acc[3]);
      acc[4]  = fmaf(xv, wi1.x, acc[4]);  acc[5]  = fmaf(xv, wi1.y, acc[5]);
      acc[6]  = fmaf(xv, wi1.z, acc[6]);  acc[7]  = fmaf(xv, wi1.w, acc[7]);
      acc[8]  = fmaf(xv, wf0.x, acc[8]);  acc[9]  = fmaf(xv, wf0.y, acc[9]);
      acc[10] = fmaf(xv, wf0.z, acc[10]); acc[11] = fmaf(xv, wf0.w, acc[11]);
      acc[12] = fmaf(xv, wf1.x, acc[12]); acc[13] = fmaf(xv, wf1.y, acc[13]);
      acc[14] = fmaf(xv, wf1.z, acc[14]); acc[15] = fmaf(xv, wf1.w, acc[15]);
    }
    #pragma unroll
    for (int o = 32; o > 0; o >>= 1){
      #pragma unroll
      for (int q = 0; q < 16; ++q) acc[q] += __shfl_xor(acc[q], o);
    }
    if (lane == 0){
      float* dst = Wc + (size_t)l*512*16 + d*16;
      #pragma unroll
      for (int q = 0; q < 16; ++q) dst[q] = acc[q];
    }
    return;
  }
  int z, t;
  if (bid < 896){ z = bid >> 7; t = bid & 127; }
  else { z = 7; t = bid - 896; }
  const float* W; unsigned short* Wt; int K, M; float scale = 1.f;
  const float INV = 0.08838834764831845f;  // 1/sqrt(128)
  switch (z){
    case 0: W = Wp;              Wt = projT0; K = 512;  M = 2048; break;
    case 1: W = Wp + 512*2048;   Wt = projT1; K = 512;  M = 2048; break;
    case 2: W = Wq;              Wt = qT0;    K = 1024; M = 1024; break;
    case 3: W = Wk;              Wt = kT0;    K = 1024; M = 1024; scale = INV; break;
    case 4: W = Wk + 1048576;    Wt = kT1;    K = 1024; M = 1024; scale = INV; break;
    case 5: W = Wv;              Wt = vT0;    K = 1024; M = 1024; break;
    case 6: W = Wv + 1048576;    Wt = vT1;    K = 1024; M = 1024; break;
    default: W = Wd;             Wt = dT0;    K = 1024; M = 512;  break;
  }
  int mtiles = M >> 6;
  int mt = t % mtiles, kt = t / mtiles;
  int m0 = mt * 64, k0 = kt * 128;
  __shared__ float s[128][65];
  int tx = threadIdx.x & 15, ty = threadIdx.x >> 4;
  #pragma unroll
  for (int u = 0; u < 128; u += 16){
    int r = u + ty;
    *(float4*)&s[r][tx*4] = *(const float4*)(W + (size_t)(k0+r)*M + m0 + tx*4);
  }
  __syncthreads();
  #pragma unroll
  for (int u = 0; u < 64; u += 16){
    int mr = u + ty;
    bf16x8 o;
    #pragma unroll
    for (int e = 0; e < 8; ++e) o[e] = (short)f2bf(s[tx*8+e][mr] * scale);
    *(bf16x8*)(Wt + (size_t)(m0+mr)*K + k0 + tx*8) = o;
  }
}

// ---------------- LayerNorm (D=512) + bf16 out + fused gate preacts ----------------
__global__ __launch_bounds__(256) void ln_gates(
    const float* __restrict__ in, unsigned short* __restrict__ outb,
    const float* __restrict__ s, const float* __restrict__ b,
    const float* __restrict__ Wc, float* __restrict__ ipfp)
{
  int r = blockIdx.x;
  const float* x = in + (size_t)r * 512;
  int tid = threadIdx.x;
  float lsum = 0.f, lsq = 0.f;
  for (int i = tid; i < 512; i += 256){ float v = x[i]; lsum += v; lsq += v*v; }
  #pragma unroll
  for (int o = 32; o > 0; o >>= 1){ lsum += __shfl_down(lsum, o); lsq += __shfl_down(lsq, o); }
  __shared__ float s1[4], s2[4];
  int wid = tid >> 6, lane = tid & 63;
  if (lane == 0){ s1[wid] = lsum; s2[wid] = lsq; }
  __syncthreads();
  if (tid == 0){ float a=0.f,c=0.f; for (int w=0; w<4; ++w){ a+=s1[w]; c+=s2[w]; } s1[0]=a; s2[0]=c; }
  __syncthreads();
  float mean = s1[0] * (1.f/512.f);
  float var  = s2[0] * (1.f/512.f) - mean*mean;
  float rstd = rsqrtf(var + 1e-5f);
  __shared__ float P[256][17];
  float g[16];
  #pragma unroll
  for (int q = 0; q < 16; ++q) g[q] = 0.f;
  for (int i = tid; i < 512; i += 256){
    float v = (x[i]-mean)*rstd*s[i] + b[i];
    outb[(size_t)r*512 + i] = f2bf(v);
    const float* wrow = Wc + i*16;
    #pragma unroll
    for (int q = 0; q < 16; ++q) g[q] = fmaf(v, wrow[q], g[q]);
  }
  #pragma unroll
  for (int q = 0; q < 16; ++q) P[tid][q] = g[q];
  __syncthreads();
  {
    int q = tid >> 4, c = tid & 15;
    float sacc = 0.f;
    #pragma unroll
    for (int u = 0; u < 16; ++u) sacc += P[c*16 + u][q];
    sacc += __shfl_xor(sacc, 1); sacc += __shfl_xor(sacc, 2);
    sacc += __shfl_xor(sacc, 4); sacc += __shfl_xor(sacc, 8);
    if (c == 0) ipfp[r*16 + q] = sacc;
  }
}

// ---------------- 128x128-tile bf16 MFMA GEMM, global_load_lds + XOR-swizzle staging ----------------
__global__ __launch_bounds__(256) void gemm_mfma128_multi(
    const unsigned short* __restrict__ A, int lda,
    const unsigned short* __restrict__ Bt0, const unsigned short* __restrict__ Bt1,
    const unsigned short* __restrict__ Bt2, int ldb,
    unsigned short* __restrict__ C0, unsigned short* __restrict__ C1,
    unsigned short* __restrict__ C2, int ldc, int K)
{
  const unsigned short* Bt = (blockIdx.z == 0) ? Bt0 : (blockIdx.z == 1) ? Bt1 : Bt2;
  unsigned short* Cbf      = (blockIdx.z == 0) ? C0  : (blockIdx.z == 1) ? C1  : C2;
  __shared__ __align__(16) unsigned short As[8192];
  __shared__ __align__(16) unsigned short Bs[8192];
  int row0 = blockIdx.y * 128, col0 = blockIdx.x * 128;
  int tid = threadIdx.x;
  int w = tid >> 6, l = tid & 63;
  int wr = (w >> 1) * 64, wc = (w & 1) * 64;
  int lrm = l & 15, lk = l >> 4;
  int lr3 = l >> 3;
  int scc = (l & 7) ^ lr3;
  f32x4 acc[4][4] = {};
  for (int k0 = 0; k0 < K; k0 += 64){
    #pragma unroll
    for (int it = 0; it < 4; ++it){
      int rowA = (it*4 + w)*8 + lr3;
      load_lds16(A  + (size_t)(row0 + rowA)*lda + k0 + scc*8, &As[(it*4 + w)*512]);
      load_lds16(Bt + (size_t)(col0 + rowA)*ldb + k0 + scc*8, &Bs[(it*4 + w)*512]);
    }
    __syncthreads();
    #pragma unroll
    for (int kk = 0; kk < 2; ++kk){
      int q = kk*4 + lk;
      bf16x8 af[4], bfr[4];
      #pragma unroll
      for (int i = 0; i < 4; ++i){
        int ra = wr + i*16 + lrm;
        af[i] = *(const bf16x8*)&As[ra*64 + ((q ^ (ra & 7)) << 3)];
      }
      #pragma unroll
      for (int j = 0; j < 4; ++j){
        int rb = wc + j*16 + lrm;
        bfr[j] = *(const bf16x8*)&Bs[rb*64 + ((q ^ (rb & 7)) << 3)];
      }
      #pragma unroll
      for (int i = 0; i < 4; ++i)
        #pragma unroll
        for (int j = 0; j < 4; ++j)
          acc[i][j] = __builtin_amdgcn_mfma_f32_16x16x32_bf16(af[i], bfr[j], acc[i][j], 0, 0, 0);
    }
    __syncthreads();
  }
  #pragma unroll
  for (int i = 0; i < 4; ++i){
    #pragma unroll
    for (int j = 0; j < 4; ++j){
      int col = col0 + wc + j*16 + lrm;
      #pragma unroll
      for (int r = 0; r < 4; ++r){
        int row = row0 + wr + i*16 + lk*4 + r;
        Cbf[(size_t)row*ldc + col] = f2bf(acc[i][j][r]);
      }
    }
  }
}

// ---------------- 64x64 bf16 MFMA GEMM (down-proj: fp32 out + skip) ----------------
__global__ __launch_bounds__(256) void gemm_mfma(
    const unsigned short* __restrict__ A, int lda,
    const unsigned short* __restrict__ Bt, int ldb,
    float* __restrict__ C, int ldc,
    unsigned short* __restrict__ Cbf,
    const float* __restrict__ skip, int ldskip,
    int K)
{
  __shared__ __align__(16) unsigned short As[64][72];
  __shared__ __align__(16) unsigned short Bs[64][72];
  int row0 = blockIdx.y * 64, col0 = blockIdx.x * 64;
  int tid = threadIdx.x;
  int w = tid >> 6, l = tid & 63;
  int wr = (w >> 1) * 32, wc = (w & 1) * 32;
  int lr = l & 15, lk = l >> 4;
  int r1 = tid >> 3, c1 = (tid & 7) * 8;
  int r2 = (tid + 256) >> 3, c2 = ((tid + 256) & 7) * 8;
  const unsigned short* a1 = A  + (size_t)(row0 + r1) * lda + c1;
  const unsigned short* a2 = A  + (size_t)(row0 + r2) * lda + c2;
  const unsigned short* b1 = Bt + (size_t)(col0 + r1) * ldb + c1;
  const unsigned short* b2 = Bt + (size_t)(col0 + r2) * ldb + c2;
  f32x4 acc00 = {0,0,0,0}, acc01 = {0,0,0,0}, acc10 = {0,0,0,0}, acc11 = {0,0,0,0};
  for (int k0 = 0; k0 < K; k0 += 64){
    *(bf16x8*)&As[r1][c1] = *(const bf16x8*)(a1 + k0);
    *(bf16x8*)&As[r2][c2] = *(const bf16x8*)(a2 + k0);
    *(bf16x8*)&Bs[r1][c1] = *(const bf16x8*)(b1 + k0);
    *(bf16x8*)&Bs[r2][c2] = *(const bf16x8*)(b2 + k0);
    __syncthreads();
    #pragma unroll
    for (int kk = 0; kk < 2; ++kk){
      bf16x8 a0 = *(const bf16x8*)&As[wr + lr][kk*32 + lk*8];
      bf16x8 a1f = *(const bf16x8*)&As[wr + 16 + lr][kk*32 + lk*8];
      bf16x8 b0 = *(const bf16x8*)&Bs[wc + lr][kk*32 + lk*8];
      bf16x8 b1f = *(const bf16x8*)&Bs[wc + 16 + lr][kk*32 + lk*8];
      acc00 = __builtin_amdgcn_mfma_f32_16x16x32_bf16(a0, b0, acc00, 0, 0, 0);
      acc01 = __builtin_amdgcn_mfma_f32_16x16x32_bf16(a0, b1f, acc01, 0, 0, 0);
      acc10 = __builtin_amdgcn_mfma_f32_16x16x32_bf16(a1f, b0, acc10, 0, 0, 0);
      acc11 = __builtin_amdgcn_mfma_f32_16x16x32_bf16(a1f, b1f, acc11, 0, 0, 0);
    }
    __syncthreads();
  }
  #pragma unroll
  for (int i = 0; i < 2; ++i){
    #pragma unroll
    for (int j = 0; j < 2; ++j){
      f32x4 a = (i == 0) ? ((j == 0) ? acc00 : acc01) : ((j == 0) ? acc10 : acc11);
      int col = col0 + wc + j*16 + lr;
      #pragma unroll
      for (int r = 0; r < 4; ++r){
        int row = row0 + wr + i*16 + lk*4 + r;
        float o = a[r];
        if (skip) o += skip[(size_t)row*ldskip + col];
        if (C)   C[(size_t)row*ldc + col] = o;
        if (Cbf) Cbf[(size_t)row*ldc + col] = f2bf(o);
      }
    }
  }
}

// ---------------- MFMA causal weighted attention (layer 0) + fused gate scan + epilogue ----------------
__global__ __launch_bounds__(256) void attn_l0_mfma(
    const unsigned short* __restrict__ q, const unsigned short* __restrict__ k,
    const unsigned short* __restrict__ v,
    const float* __restrict__ ipfp, const float* __restrict__ bi, const float* __restrict__ bfg,
    const unsigned short* __restrict__ xpb,
    const float* __restrict__ gn_s, const float* __restrict__ gn_b,
    unsigned short* __restrict__ gated)
{
  __shared__ __align__(16) char smem[48128];
  unsigned short (*Ks)[136] = (unsigned short(*)[136])smem;
  unsigned short (*Vt)[72]  = (unsigned short(*)[72])(smem + 17408);
  unsigned short (*Ps)[72]  = (unsigned short(*)[72])(smem + 35840);
  float* invden = (float*)(smem + 45056);
  float (*denL)[64] = (float(*)[64])(smem + 45568);
  float* alpha_full = (float*)(smem + 46080);
  float* Mt_full    = (float*)(smem + 47104);
  float (*numf)[140] = (float(*)[140])smem;

  int blk = blockIdx.x;
  int tt = blk & 3, h = (blk >> 2) & 7, b = blk >> 5;
  int t0 = tt * 64;
  int tid = threadIdx.x;
  int w = tid >> 6, l = tid & 63;
  int wr = (w >> 1) * 32;
  int wc = (w & 1) * 32;
  int wd = (w & 1) * 64;
  int lrm = l & 15, lk = l >> 4;
  size_t headoff = (size_t)h * 128;

  {
    #pragma unroll
    for (int u = 0; u < 4; ++u){
      int o = u*256 + tid, row = o >> 4, oct = o & 15;
      *(bf16x8*)&Ks[row][oct*8] =
        *(const bf16x8*)(q + (size_t)(b*256 + t0 + row)*1024 + headoff + oct*8);
    }
    if (tid < 64){
      int lane = tid;
      float bih = bi[h], bfh = bfg[h];
      float lf[4], ip4[4];
      #pragma unroll
      for (int u = 0; u < 4; ++u){
        int r = b*256 + lane*4 + u;
        ip4[u] = ipfp[r*16 + h] + bih;
        lf[u]  = logsig_f(ipfp[r*16 + 8 + h] + bfh);
      }
      float c0 = lf[0], c1 = c0+lf[1], c2 = c1+lf[2], c3 = c2+lf[3];
      float tot = c3, pre = tot;
      #pragma unroll
      for (int o = 1; o < 64; o <<= 1){ float vv = __shfl_up(pre, o); if (lane >= o) pre += vv; }
      float excl = pre - tot;
      float al[4] = { ip4[0]-(excl+c0), ip4[1]-(excl+c1), ip4[2]-(excl+c2), ip4[3]-(excl+c3) };
      float lm[4];
      lm[0]=al[0]; lm[1]=fmaxf(lm[0],al[1]); lm[2]=fmaxf(lm[1],al[2]); lm[3]=fmaxf(lm[2],al[3]);
      float pm = lm[3];
      #pragma unroll
      for (int o = 1; o < 64; o <<= 1){ float vv = __shfl_up(pm, o); if (lane >= o) pm = fmaxf(pm, vv); }
      float pmexcl = __shfl_up(pm, 1);
      if (lane == 0) pmexcl = -3.4e38f;
      #pragma unroll
      for (int u = 0; u < 4; ++u){
        alpha_full[lane*4+u] = al[u];
        Mt_full[lane*4+u] = fmaxf(0.f, fmaxf(pmexcl, lm[u]));
      }
    }
    if (tid < 128) ((float*)denL)[tid] = 0.f;
  }
  __syncthreads();
  bf16x8 aq[2][4];
  #pragma unroll
  for (int i = 0; i < 2; ++i)
    #pragma unroll
    for (int kk = 0; kk < 4; ++kk)
      aq[i][kk] = *(const bf16x8*)&Ks[wr + i*16 + lrm][kk*32 + lk*8];
  __syncthreads();

  f32x4 pacc[2][4] = {};
  int ntile = tt + 1;

  for (int it = 0; it < ntile; ++it){
    int s0 = it * 64;
    #pragma unroll
    for (int u = 0; u < 4; ++u){
      int o = u*256 + tid, row = o >> 4, oct = o & 15;
      *(bf16x8*)&Ks[row][oct*8] =
        *(const bf16x8*)(k + (size_t)(b*256 + s0 + row)*1024 + headoff + oct*8);
    }
    #pragma unroll
    for (int u = 0; u < 2; ++u){
      int task = u*256 + tid;
      int sp = task & 31, oct = task >> 5;
      const unsigned short* vp = v + (size_t)(b*256 + s0 + sp*2)*1024 + headoff + oct*8;
      bf16x8 r0 = *(const bf16x8*)vp;
      bf16x8 r1 = *(const bf16x8*)(vp + 1024);
      #pragma unroll
      for (int j = 0; j < 8; ++j){
        unsigned lo = (unsigned short)r0[j];
        unsigned hi = (unsigned short)r1[j];
        *(unsigned*)&Vt[oct*8 + j][sp*2] = lo | (hi << 16);
      }
    }
    __syncthreads();

    f32x4 sacc[2][2] = {};
    #pragma unroll
    for (int kk = 0; kk < 4; ++kk){
      bf16x8 b0 = *(const bf16x8*)&Ks[wc + lrm][kk*32 + lk*8];
      bf16x8 b1 = *(const bf16x8*)&Ks[wc + 16 + lrm][kk*32 + lk*8];
      sacc[0][0] = __builtin_amdgcn_mfma_f32_16x16x32_bf16(aq[0][kk], b0, sacc[0][0], 0, 0, 0);
      sacc[0][1] = __builtin_amdgcn_mfma_f32_16x16x32_bf16(aq[0][kk], b1, sacc[0][1], 0, 0, 0);
      sacc[1][0] = __builtin_amdgcn_mfma_f32_16x16x32_bf16(aq[1][kk], b0, sacc[1][0], 0, 0, 0);
      sacc[1][1] = __builtin_amdgcn_mfma_f32_16x16x32_bf16(aq[1][kk], b1, sacc[1][1], 0, 0, 0);
    }

    bool diag = (it == ntile - 1);
    float av0 = alpha_full[s0 + wc + lrm];
    float av1 = alpha_full[s0 + wc + 16 + lrm];
    #pragma unroll
    for (int i = 0; i < 2; ++i){
      #pragma unroll
      for (int r = 0; r < 4; ++r){
        int tl = wr + i*16 + lk*4 + r;
        float mt = Mt_full[t0 + tl];
        float p0 = __expf(av0 - mt) * sacc[i][0][r];
        float p1 = __expf(av1 - mt) * sacc[i][1][r];
        if (diag){
          if (wc + lrm      > tl) p0 = 0.f;
          if (wc + 16 + lrm > tl) p1 = 0.f;
        }
        Ps[tl][wc + lrm]      = f2bf(p0);
        Ps[tl][wc + 16 + lrm] = f2bf(p1);
        float dv = p0 + p1;
        dv += __shfl_xor(dv, 1); dv += __shfl_xor(dv, 2);
        dv += __shfl_xor(dv, 4); dv += __shfl_xor(dv, 8);
        if (lrm == 0) denL[w & 1][tl] += dv;
      }
    }
    __syncthreads();

    #pragma unroll
    for (int ks = 0; ks < 2; ++ks){
      bf16x8 pa0 = *(const bf16x8*)&Ps[wr + lrm][ks*32 + lk*8];
      bf16x8 pa1 = *(const bf16x8*)&Ps[wr + 16 + lrm][ks*32 + lk*8];
      #pragma unroll
      for (int jd = 0; jd < 4; ++jd){
        bf16x8 vb8 = *(const bf16x8*)&Vt[wd + jd*16 + lrm][ks*32 + lk*8];
        pacc[0][jd] = __builtin_amdgcn_mfma_f32_16x16x32_bf16(pa0, vb8, pacc[0][jd], 0, 0, 0);
        pacc[1][jd] = __builtin_amdgcn_mfma_f32_16x16x32_bf16(pa1, vb8, pacc[1][jd], 0, 0, 0);
      }
    }
    __syncthreads();
  }

  #pragma unroll
  for (int i = 0; i < 2; ++i)
    #pragma unroll
    for (int jd = 0; jd < 4; ++jd)
      #pragma unroll
      for (int r = 0; r < 4; ++r)
        numf[wr + i*16 + lk*4 + r][wd + jd*16 + lrm] = pacc[i][jd][r];
  if (tid < 64){
    float s = denL[0][tid] + denL[1][tid];
    invden[tid] = 1.0f / fmaxf(fabsf(s), 1.0f);
  }
  __syncthreads();

  {
    int row = tid >> 2, qq = tid & 3;
    float inv = invden[row];
    const float* nr = &numf[row][qq*32];
    float xs[32];
    float sum = 0.f, sq = 0.f;
    #pragma unroll
    for (int j = 0; j < 8; ++j){
      float4 t4 = *(const float4*)(nr + j*4);
      float v0 = t4.x*inv, v1 = t4.y*inv, v2 = t4.z*inv, v3 = t4.w*inv;
      xs[j*4+0] = v0; xs[j*4+1] = v1; xs[j*4+2] = v2; xs[j*4+3] = v3;
      sum += v0+v1+v2+v3;
      sq  += v0*v0+v1*v1+v2*v2+v3*v3;
    }
    sum += __shfl_xor(sum, 1); sq += __shfl_xor(sq, 1);
    sum += __shfl_xor(sum, 2); sq += __shfl_xor(sq, 2);
    float mean = sum * (1.f/128.f);
    float var  = sq  * (1.f/128.f) - mean*mean;
    float rstd = rsqrtf(var + 1e-5f);
    int rr = b*256 + t0 + row;
    const unsigned short* zp = xpb + (size_t)rr*2048 + 1024 + headoff + qq*32;
    const float* gsP = gn_s + headoff + qq*32;
    const float* gbP = gn_b + headoff + qq*32;
    unsigned short* op = gated + (size_t)rr*1024 + headoff + qq*32;
    #pragma unroll
    for (int j8 = 0; j8 < 4; ++j8){
      bf16x8 zv = *(const bf16x8*)(zp + j8*8);
      bf16x8 ov;
      #pragma unroll
      for (int j = 0; j < 8; ++j){
        int jj = j8*8 + j;
        float valn = (xs[jj]-mean)*rstd*gsP[jj] + gbP[jj];
        ov[j] = (short)f2bf(valn * silu_f(bf2f((unsigned short)zv[j])));
      }
      *(bf16x8*)(op + j8*8) = ov;
    }
  }
}

// ---------------- layer 1 q at last step: split-K GEMV (fp32 Wq, coalesced) ----------------
__global__ void qlast_split(const unsigned short* __restrict__ xpb, const float* __restrict__ Wq1,
                            float* __restrict__ part)
{
  int jt = blockIdx.x, ks = blockIdx.y;      // (4, 32)
  int j = jt*256 + threadIdx.x;
  __shared__ float xs[4][32];
  int t = threadIdx.x;
  if (t < 128){ int b = t >> 5, kk = t & 31; xs[b][kk] = bf2f(xpb[(size_t)(b*256+255)*2048 + ks*32 + kk]); }
  __syncthreads();
  float a0=0.f,a1=0.f,a2=0.f,a3=0.f;
  #pragma unroll 8
  for (int kk = 0; kk < 32; ++kk){
    float wv = Wq1[(size_t)(ks*32+kk)*1024 + j];
    a0 = fmaf(xs[0][kk], wv, a0);
    a1 = fmaf(xs[1][kk], wv, a1);
    a2 = fmaf(xs[2][kk], wv, a2);
    a3 = fmaf(xs[3][kk], wv, a3);
  }
  part[((size_t)ks*4 + 0)*1024 + j] = a0;
  part[((size_t)ks*4 + 1)*1024 + j] = a1;
  part[((size_t)ks*4 + 2)*1024 + j] = a2;
  part[((size_t)ks*4 + 3)*1024 + j] = a3;
}

// ---------------- layer 1 last-step attention + fused per-bh finalize (last-block-done) ----------------
__global__ __launch_bounds__(256) void attn_l1_split(
    const float* __restrict__ qpart, const unsigned short* __restrict__ k1,
    const unsigned short* __restrict__ v1,
    const float* __restrict__ ipfp, const float* __restrict__ bi, const float* __restrict__ bfg,
    const unsigned short* __restrict__ xpb,
    const float* __restrict__ gn_s, const float* __restrict__ gn_b,
    float* __restrict__ pnum, float* __restrict__ pden,
    float* __restrict__ gated1, unsigned* __restrict__ cnts)
{
  int sc = blockIdx.x, bh = blockIdx.y;      // (8, 32)
  int b = bh >> 3, h = bh & 7;
  int s0 = sc * 32;
  int tid = threadIdx.x;
  __shared__ float qsh[128];
  __shared__ float alpha256[256];
  __shared__ float mt255s;
  __shared__ float sred[32][9];
  __shared__ float as[32];
  __shared__ float nred[2][128];
  if (tid < 128){
    float s = 0.f;
    #pragma unroll 8
    for (int ks = 0; ks < 32; ++ks) s += qpart[((size_t)ks*4 + b)*1024 + h*128 + tid];
    qsh[tid] = s;
  }
  if (tid >= 128 && tid < 192){
    int lane = tid - 128;
    float bih = bi[h], bfh = bfg[h];
    float lf[4], ip4[4];
    #pragma unroll
    for (int u = 0; u < 4; ++u){
      int r = b*256 + lane*4 + u;
      ip4[u] = ipfp[r*16 + h] + bih;
      lf[u]  = logsig_f(ipfp[r*16 + 8 + h] + bfh);
    }
    float c0 = lf[0], c1 = c0+lf[1], c2 = c1+lf[2], c3 = c2+lf[3];
    float tot = c3, pre = tot;
    #pragma unroll
    for (int o = 1; o < 64; o <<= 1){ float vv = __shfl_up(pre, o); if (lane >= o) pre += vv; }
    float excl = pre - tot;
    float al[4] = { ip4[0]-(excl+c0), ip4[1]-(excl+c1), ip4[2]-(excl+c2), ip4[3]-(excl+c3) };
    #pragma unroll
    for (int u = 0; u < 4; ++u) alpha256[lane*4+u] = al[u];
    float mx = fmaxf(fmaxf(al[0],al[1]), fmaxf(al[2],al[3]));
    #pragma unroll
    for (int o = 32; o > 0; o >>= 1) mx = fmaxf(mx, __shfl_xor(mx, o));
    if (lane == 0) mt255s = fmaxf(0.f, mx);
  }
  __syncthreads();
  {
    int sl = tid & 31, dc = tid >> 5;
    const unsigned short* kp = k1 + (size_t)(b*256 + s0 + sl)*1024 + h*128 + dc*16;
    float p = 0.f;
    #pragma unroll
    for (int u = 0; u < 16; u += 8){
      bf16x8 kv = *(const bf16x8*)(kp + u);
      #pragma unroll
      for (int e = 0; e < 8; ++e) p = fmaf(qsh[dc*16+u+e], bf2f((unsigned short)kv[e]), p);
    }
    sred[sl][dc] = p;
  }
  __syncthreads();
  if (tid < 32){
    float sum = 0.f;
    #pragma unroll
    for (int dc = 0; dc < 8; ++dc) sum += sred[tid][dc];
    float w = __expf(alpha256[s0 + tid] - mt255s);
    as[tid] = w * sum;
  }
  __syncthreads();
  {
    int d = tid & 127, sg = tid >> 7;
    const unsigned short* vp = v1 + (size_t)(b*256 + s0 + sg*16)*1024 + h*128 + d;
    float np = 0.f;
    #pragma unroll
    for (int u = 0; u < 16; ++u) np = fmaf(as[sg*16 + u], bf2f(vp[(size_t)u*1024]), np);
    nred[sg][d] = np;
  }
  __syncthreads();
  if (tid < 128) pnum[((size_t)bh*8 + sc)*128 + tid] = nred[0][tid] + nred[1][tid];
  if (tid == 128){
    float dsum = 0.f;
    #pragma unroll
    for (int u = 0; u < 32; ++u) dsum += as[u];
    pden[bh*8 + sc] = dsum;
  }
  // ---- last-block-done finalize for this bh ----
  __threadfence();
  __shared__ int lastF;
  if (tid == 0) lastF = (atomicAdd(&cnts[2 + bh], 1u) == 7u) ? 1 : 0;
  __syncthreads();
  if (!lastF) return;
  __shared__ float hh2[128];
  __shared__ float dsh2, msh2, rsh2;
  if (tid == 0){
    float d = 0.f;
    #pragma unroll
    for (int s2 = 0; s2 < 8; ++s2) d += pden[bh*8 + s2];
    dsh2 = fmaxf(fabsf(d), 1.0f);
  }
  __syncthreads();
  if (tid < 128){
    float nsum = 0.f;
    #pragma unroll
    for (int s2 = 0; s2 < 8; ++s2) nsum += pnum[((size_t)bh*8 + s2)*128 + tid];
    hh2[tid] = nsum / dsh2;
  }
  __syncthreads();
  if (tid < 64){
    float a = hh2[tid], c = hh2[tid + 64];
    float s1 = a + c, s2v = a*a + c*c;
    #pragma unroll
    for (int o = 32; o > 0; o >>= 1){ s1 += __shfl_down(s1, o); s2v += __shfl_down(s2v, o); }
    if (tid == 0){
      float mean = s1*(1.f/128.f);
      float var  = s2v*(1.f/128.f) - mean*mean;
      msh2 = mean; rsh2 = rsqrtf(var + 1e-5f);
    }
  }
  __syncthreads();
  if (tid < 128){
    int i = h*128 + tid;
    float valn = (hh2[tid] - msh2)*rsh2*gn_s[i] + gn_b[i];
    float z = bf2f(xpb[(size_t)(b*256 + 255)*2048 + 1024 + i]);
    gated1[b*1024 + i] = valn * silu_f(z);
  }
}

// ---------------- last-step down proj + LN + pi head (split-K + last-block finalize) ----------------
__global__ __launch_bounds__(256) void dl_all(
    const float* __restrict__ gated1, const float* __restrict__ Wd,
    const float* __restrict__ h0,
    const float* __restrict__ fln_s, const float* __restrict__ fln_b,
    const float* __restrict__ W_pi, const float* __restrict__ b_pi,
    float* __restrict__ part, float* __restrict__ lastb, float* __restrict__ out,
    unsigned* __restrict__ cnts)
{
  int jt = blockIdx.x, ks = blockIdx.y;      // (2, 32)
  int j = jt*256 + threadIdx.x;
  int tid = threadIdx.x;
  __shared__ float xs[4][32];
  if (tid < 128){ int b = tid >> 5, kk = tid & 31; xs[b][kk] = gated1[b*1024 + ks*32 + kk]; }
  __syncthreads();
  float a0=0.f,a1=0.f,a2=0.f,a3=0.f;
  #pragma unroll 8
  for (int kk = 0; kk < 32; ++kk){
    float wv = Wd[(size_t)(ks*32+kk)*512 + j];
    a0 = fmaf(xs[0][kk], wv, a0);
    a1 = fmaf(xs[1][kk], wv, a1);
    a2 = fmaf(xs[2][kk], wv, a2);
    a3 = fmaf(xs[3][kk], wv, a3);
  }
  part[((size_t)ks*4 + 0)*512 + j] = a0;
  part[((size_t)ks*4 + 1)*512 + j] = a1;
  part[((size_t)ks*4 + 2)*512 + j] = a2;
  part[((size_t)ks*4 + 3)*512 + j] = a3;
  __threadfence();
  __shared__ int lastF;
  if (tid == 0) lastF = (atomicAdd(&cnts[0], 1u) == 63u) ? 1 : 0;
  __syncthreads();
  if (!lastF) return;
  // finalize: all 4 batches, LN + pi
  __shared__ float ls2[512];
  __shared__ float pred2[8][33];
  __shared__ float s1[4], s2[4];
  for (int b2 = 0; b2 < 4; ++b2){
    float v[2];
    #pragma unroll
    for (int u = 0; u < 2; ++u){
      int jj = tid*2 + u;
      float s = 0.f;
      #pragma unroll 8
      for (int k2 = 0; k2 < 32; ++k2) s += part[((size_t)k2*4 + b2)*512 + jj];
      v[u] = h0[(size_t)(b2*256 + 255)*512 + jj] + s;
    }
    float lsum = v[0] + v[1], lsq = v[0]*v[0] + v[1]*v[1];
    #pragma unroll
    for (int o = 32; o > 0; o >>= 1){ lsum += __shfl_down(lsum, o); lsq += __shfl_down(lsq, o); }
    int wid = tid >> 6, lane = tid & 63;
    if (lane == 0){ s1[wid] = lsum; s2[wid] = lsq; }
    __syncthreads();
    if (tid == 0){ float a=0.f,c=0.f; for (int w2=0; w2<4; ++w2){ a+=s1[w2]; c+=s2[w2]; } s1[0]=a; s2[0]=c; }
    __syncthreads();
    float mean = s1[0] * (1.f/512.f);
    float var  = s2[0] * (1.f/512.f) - mean*mean;
    float rstd = rsqrtf(var + 1e-5f);
    #pragma unroll
    for (int u = 0; u < 2; ++u){
      int jj = tid*2 + u;
      float lv = (v[u]-mean)*rstd*fln_s[jj] + fln_b[jj];
      lastb[b2*512 + jj] = lv;
      ls2[jj] = lv;
    }
    __syncthreads();
    {
      int o = tid & 31, pt = tid >> 5;
      float pa = 0.f;
      #pragma unroll 8
      for (int u = 0; u < 64; ++u){ int i = pt*64 + u; pa = fmaf(ls2[i], W_pi[i*32 + o], pa); }
      pred2[pt][o] = pa;
    }
    __syncthreads();
    if (tid < 32){
      float acc = b_pi[tid];
      #pragma unroll
      for (int pt = 0; pt < 8; ++pt) acc += pred2[pt][tid];
      float m = acc;
      #pragma unroll
      for (int o2 = 16; o2 > 0; o2 >>= 1) m = fmaxf(m, __shfl_xor(m, o2));
      float e = __expf(acc - m);
      float ss = e;
      #pragma unroll
      for (int o2 = 16; o2 > 0; o2 >>= 1) ss += __shfl_xor(ss, o2);
      out[b2*32 + tid] = e / ss;
    }
    __syncthreads();
  }
}

// ---------------- MDN mu/sigma heads: split-K + last-block reduce ----------------
__global__ __launch_bounds__(256) void ms_all(
    const float* __restrict__ last,
    const float* __restrict__ W_mu, const float* __restrict__ W_sig,
    const float* __restrict__ b_mu, const float* __restrict__ b_sig,
    float* __restrict__ part, float* __restrict__ out,
    unsigned* __restrict__ cnts)
{
  int jt = blockIdx.x, ks = blockIdx.y, mat = blockIdx.z;  // (8, 8, 2)
  int tid = threadIdx.x;
  int j = jt*256 + tid;
  const float* W = mat ? W_sig : W_mu;
  __shared__ float xs[4][64];
  { int b = tid >> 6, kk = tid & 63; xs[b][kk] = last[b*512 + ks*64 + kk]; }
  __syncthreads();
  float a0=0.f,a1=0.f,a2=0.f,a3=0.f;
  #pragma unroll 8
  for (int kk = 0; kk < 64; ++kk){
    float wv = W[(size_t)(ks*64+kk)*2048 + j];
    a0 = fmaf(xs[0][kk], wv, a0);
    a1 = fmaf(xs[1][kk], wv, a1);
    a2 = fmaf(xs[2][kk], wv, a2);
    a3 = fmaf(xs[3][kk], wv, a3);
  }
  size_t base = ((size_t)(mat*8 + ks)*4);
  part[(base + 0)*2048 + j] = a0;
  part[(base + 1)*2048 + j] = a1;
  part[(base + 2)*2048 + j] = a2;
  part[(base + 3)*2048 + j] = a3;
  __threadfence();
  __shared__ int lastF;
  if (tid == 0) lastF = (atomicAdd(&cnts[1], 1u) == 127u) ? 1 : 0;
  __syncthreads();
  if (!lastF) return;
  for (int it2 = 0; it2 < 8; ++it2){
    int jj = it2*256 + tid;    // 0..2047
    #pragma unroll
    for (int m2 = 0; m2 < 2; ++m2){
      float bias = (m2 ? b_sig : b_mu)[jj];
      #pragma unroll
      for (int b2 = 0; b2 < 4; ++b2){
        float s = bias;
        #pragma unroll
        for (int k2 = 0; k2 < 8; ++k2) s += part[((size_t)(m2*8 + k2)*4 + b2)*2048 + jj];
        out[128 + m2*8192 + b2*2048 + jj] = m2 ? softplus_f(s) : s;
      }
    }
  }
}

// ---------------- launch ----------------
extern "C" void kernel_launch(void* const* d_in, const int* in_sizes, int n_in,
                              void* d_out, int out_size, void* d_ws, size_t ws_size,
                              hipStream_t stream)
{
  const float* x      = (const float*)d_in[0];
  const float* ln_s   = (const float*)d_in[1];
  const float* ln_b   = (const float*)d_in[2];
  const float* W_proj = (const float*)d_in[3];
  const float* Wq     = (const float*)d_in[4];
  const float* Wk     = (const float*)d_in[5];
  const float* Wv     = (const float*)d_in[6];
  const float* Wi     = (const float*)d_in[7];
  const float* bi     = (const float*)d_in[8];
  const float* Wf     = (const float*)d_in[9];
  const float* bf     = (const float*)d_in[10];
  const float* gn_s   = (const float*)d_in[11];
  const float* gn_b   = (const float*)d_in[12];
  const float* W_down = (const float*)d_in[13];
  const float* fln_s  = (const float*)d_in[14];
  const float* fln_b  = (const float*)d_in[15];
  const float* W_pi   = (const float*)d_in[16];
  const float* b_pi   = (const float*)d_in[17];
  const float* W_mu   = (const float*)d_in[18];
  const float* b_mu   = (const float*)d_in[19];
  const float* W_sig  = (const float*)d_in[20];
  const float* b_sig  = (const float*)d_in[21];
  float* out = (float*)d_out;

  char* p = (char*)d_ws;
  unsigned short* projT0 = (unsigned short*)p; p += (size_t)2048*512*2;
  unsigned short* projT1 = (unsigned short*)p; p += (size_t)2048*512*2;
  unsigned short* qT0    = (unsigned short*)p; p += (size_t)1024*1024*2;
  unsigned short* kT0    = (unsigned short*)p; p += (size_t)1024*1024*2;
  unsigned short* kT1    = (unsigned short*)p; p += (size_t)1024*1024*2;
  unsigned short* vT0    = (unsigned short*)p; p += (size_t)1024*1024*2;
  unsigned short* vT1    = (unsigned short*)p; p += (size_t)1024*1024*2;
  unsigned short* dT0    = (unsigned short*)p; p += (size_t)512*1024*2;
  float* Wc              = (float*)p;          p += (size_t)2*512*16*4;
  unsigned short* xnb    = (unsigned short*)p; p += (size_t)1024*512*2;
  unsigned short* xpb    = (unsigned short*)p; p += (size_t)1024*2048*2;
  unsigned short* qbb    = (unsigned short*)p; p += (size_t)1024*1024*2;
  unsigned short* kbb    = (unsigned short*)p; p += (size_t)1024*1024*2;
  unsigned short* vbb    = (unsigned short*)p; p += (size_t)1024*1024*2;
  unsigned short* gatedb = (unsigned short*)p; p += (size_t)1024*1024*2;
  float* h0     = (float*)p; p += (size_t)1024*512*4;
  float* ipfp   = (float*)p; p += (size_t)16384*4;
  float* gated1 = (float*)p; p += (size_t)4096*4;
  float* lastb  = (float*)p; p += (size_t)2048*4;
  float* qpart  = (float*)p; p += (size_t)32*4096*4;
  float* dpart  = (float*)p; p += (size_t)32*4*512*4;
  float* pnum   = (float*)p; p += (size_t)32*8*128*4;
  float* pden   = (float*)p; p += (size_t)32*8*4;
  float* mspart = (float*)p; p += (size_t)16*4*2048*4;
  unsigned* cnts = (unsigned*)p; p += 64*4;

  const float* ln_s1 = ln_s + 512;
  const float* ln_b1 = ln_b + 512;
  const float* gn_s1 = gn_s + 1024;
  const float* gn_b1 = gn_b + 1024;
  const float* Wq1   = Wq + 1024*1024;
  const float* Wd1   = W_down + 1024*512;

  dim3 blk256(256);

  // weight prep (960 transpose tiles + 256 compose blocks; also zeroes sync counters)
  wprep<<<1216, blk256, 0, stream>>>(W_proj, Wq, Wk, Wv, W_down, Wi, Wf,
      projT0, projT1, qT0, kT0, kT1, vT0, vT1, dT0, Wc, cnts);

  // ---------- layer 0 ----------
  ln_gates<<<1024, blk256, 0, stream>>>(x, xnb, ln_s, ln_b, Wc, ipfp);
  gemm_mfma128_multi<<<dim3(16,8,1), blk256, 0, stream>>>(xnb, 512, projT0, projT0, projT0, 512, xpb, xpb, xpb, 2048, 512);
  gemm_mfma128_multi<<<dim3(8,8,3), blk256, 0, stream>>>(xpb, 2048, qT0, kT0, vT0, 1024, qbb, kbb, vbb, 1024, 1024);
  attn_l0_mfma<<<128, blk256, 0, stream>>>(qbb, kbb, vbb, ipfp, bi, bf, xpb, gn_s, gn_b, gatedb);
  gemm_mfma<<<dim3(8,16), blk256, 0, stream>>>(gatedb, 1024, dT0, 1024, h0, 512, nullptr, x, 512, 1024);

  // ---------- layer 1 ----------
  ln_gates<<<1024, blk256, 0, stream>>>(h0, xnb, ln_s1, ln_b1, Wc + 512*16, ipfp);
  gemm_mfma128_multi<<<dim3(16,8,1), blk256, 0, stream>>>(xnb, 512, projT1, projT1, projT1, 512, xpb, xpb, xpb, 2048, 512);
  gemm_mfma128_multi<<<dim3(8,8,2), blk256, 0, stream>>>(xpb, 2048, kT1, vT1, vT1, 1024, kbb, vbb, vbb, 1024, 1024);
  qlast_split<<<dim3(4,32), blk256, 0, stream>>>(xpb, Wq1, qpart);
  attn_l1_split<<<dim3(8,32), blk256, 0, stream>>>(qpart, kbb, vbb, ipfp, bi + 8, bf + 8,
      xpb, gn_s1, gn_b1, pnum, pden, gated1, cnts);
  dl_all<<<dim3(2,32), blk256, 0, stream>>>(gated1, Wd1, h0, fln_s, fln_b, W_pi, b_pi,
      dpart, lastb, out, cnts);

  // ---------- final head ----------
  ms_all<<<dim3(8,8,2), blk256, 0, stream>>>(lastb, W_mu, W_sig, b_mu, b_sig, mspart, out, cnts);
}

// Round 14
// 186.113 us; speedup vs baseline: 1.9041x; 1.9041x over previous
//
#include <hip/hip_runtime.h>
#include <hip/hip_bf16.h>
#include <math.h>

#define DEV __device__ __forceinline__

typedef __attribute__((ext_vector_type(8))) short bf16x8;
typedef __attribute__((ext_vector_type(4))) float f32x4;

static DEV float softplus_f(float x){ return fmaxf(x,0.f) + log1pf(expf(-fabsf(x))); }
static DEV float logsig_f(float x){ return fminf(x,0.f) - log1pf(expf(-fabsf(x))); }
static DEV float silu_f(float x){ return x / (1.f + expf(-x)); }
static DEV unsigned short f2bf(float f){
  union { float f; unsigned u; } v; v.f = f;
  unsigned r = (v.u + 0x7fffu + ((v.u >> 16) & 1u)) >> 16;
  return (unsigned short)r;
}
static DEV float bf2f(unsigned short u){
  union { unsigned u; float f; } v; v.u = ((unsigned)u) << 16; return v.f;
}

// ---------------- weight prep: 960 transpose tiles (64m x 128k) + 256 compose blocks ----------------
__global__ __launch_bounds__(256) void wprep(
    const float* __restrict__ Wp, const float* __restrict__ Wq,
    const float* __restrict__ Wk, const float* __restrict__ Wv,
    const float* __restrict__ Wd, const float* __restrict__ Wi,
    const float* __restrict__ Wf,
    unsigned short* projT0, unsigned short* projT1,
    unsigned short* qT0, unsigned short* kT0, unsigned short* kT1,
    unsigned short* vT0, unsigned short* vT1, unsigned short* dT0,
    float* __restrict__ Wc)
{
  int bid = blockIdx.x;
  if (bid >= 960){
    int fb = bid - 960;                       // 0..255
    int gid = fb * 4 + (threadIdx.x >> 6);    // 0..1023
    int l = gid >> 9, d = gid & 511;
    int lane = threadIdx.x & 63;
    const float* wp = Wp + (size_t)l*512*2048 + (size_t)d*2048 + lane*16;
    const float* wi = Wi + (size_t)l*1024*8;
    const float* wf = Wf + (size_t)l*1024*8;
    float acc[16];
    #pragma unroll
    for (int q = 0; q < 16; ++q) acc[q] = 0.f;
    #pragma unroll 4
    for (int u = 0; u < 16; ++u){
      float xv = wp[u];
      int j = lane*16 + u;
      float4 wi0 = *(const float4*)(wi + j*8);
      float4 wi1 = *(const float4*)(wi + j*8 + 4);
      float4 wf0 = *(const float4*)(wf + j*8);
      float4 wf1 = *(const float4*)(wf + j*8 + 4);
      acc[0]  = fmaf(xv, wi0.x, acc[0]);  acc[1]  = fmaf(xv, wi0.y, acc[1]);
      acc[2]  = fmaf(xv, wi0.z, acc[2]);  acc[3]  = fmaf(xv, wi0.w, acc[3]);
      acc[4]  = fmaf(xv, wi1.x, acc[4]);  acc[5]  = fmaf(xv, wi1.y, acc[5]);
      acc[6]  = fmaf(xv, wi1.z, acc[6]);  acc[7]  = fmaf(xv, wi1.w, acc[7]);
      acc[8]  = fmaf(xv, wf0.x, acc[8]);  acc[9]  = fmaf(xv, wf0.y, acc[9]);
      acc[10] = fmaf(xv, wf0.z, acc[10]); acc[11] = fmaf(xv, wf0.w, acc[11]);
      acc[12] = fmaf(xv, wf1.x, acc[12]); acc[13] = fmaf(xv, wf1.y, acc[13]);
      acc[14] = fmaf(xv, wf1.z, acc[14]); acc[15] = fmaf(xv, wf1.w, acc[15]);
    }
    #pragma unroll
    for (int o = 32; o > 0; o >>= 1){
      #pragma unroll
      for (int q = 0; q < 16; ++q) acc[q] += __shfl_xor(acc[q], o);
    }
    if (lane == 0){
      float* dst = Wc + (size_t)l*512*16 + d*16;
      #pragma unroll
      for (int q = 0; q < 16; ++q) dst[q] = acc[q];
    }
    return;
  }
  int z, t;
  if (bid < 896){ z = bid >> 7; t = bid & 127; }
  else { z = 7; t = bid - 896; }
  const float* W; unsigned short* Wt; int K, M; float scale = 1.f;
  const float INV = 0.08838834764831845f;  // 1/sqrt(128)
  switch (z){
    case 0: W = Wp;              Wt = projT0; K = 512;  M = 2048; break;
    case 1: W = Wp + 512*2048;   Wt = projT1; K = 512;  M = 2048; break;
    case 2: W = Wq;              Wt = qT0;    K = 1024; M = 1024; break;
    case 3: W = Wk;              Wt = kT0;    K = 1024; M = 1024; scale = INV; break;
    case 4: W = Wk + 1048576;    Wt = kT1;    K = 1024; M = 1024; scale = INV; break;
    case 5: W = Wv;              Wt = vT0;    K = 1024; M = 1024; break;
    case 6: W = Wv + 1048576;    Wt = vT1;    K = 1024; M = 1024; break;
    default: W = Wd;             Wt = dT0;    K = 1024; M = 512;  break;
  }
  int mtiles = M >> 6;
  int mt = t % mtiles, kt = t / mtiles;
  int m0 = mt * 64, k0 = kt * 128;
  __shared__ float s[128][65];
  int tx = threadIdx.x & 15, ty = threadIdx.x >> 4;
  #pragma unroll
  for (int u = 0; u < 128; u += 16){
    int r = u + ty;
    *(float4*)&s[r][tx*4] = *(const float4*)(W + (size_t)(k0+r)*M + m0 + tx*4);
  }
  __syncthreads();
  #pragma unroll
  for (int u = 0; u < 64; u += 16){
    int mr = u + ty;
    bf16x8 o;
    #pragma unroll
    for (int e = 0; e < 8; ++e) o[e] = (short)f2bf(s[tx*8+e][mr] * scale);
    *(bf16x8*)(Wt + (size_t)(m0+mr)*K + k0 + tx*8) = o;
  }
}

// ---------------- LayerNorm (D=512) + bf16 out + fused gate preacts ----------------
__global__ __launch_bounds__(256) void ln_gates(
    const float* __restrict__ in, unsigned short* __restrict__ outb,
    const float* __restrict__ s, const float* __restrict__ b,
    const float* __restrict__ Wc, float* __restrict__ ipfp)
{
  int r = blockIdx.x;
  const float* x = in + (size_t)r * 512;
  int tid = threadIdx.x;
  float lsum = 0.f, lsq = 0.f;
  for (int i = tid; i < 512; i += 256){ float v = x[i]; lsum += v; lsq += v*v; }
  #pragma unroll
  for (int o = 32; o > 0; o >>= 1){ lsum += __shfl_down(lsum, o); lsq += __shfl_down(lsq, o); }
  __shared__ float s1[4], s2[4];
  int wid = tid >> 6, lane = tid & 63;
  if (lane == 0){ s1[wid] = lsum; s2[wid] = lsq; }
  __syncthreads();
  if (tid == 0){ float a=0.f,c=0.f; for (int w=0; w<4; ++w){ a+=s1[w]; c+=s2[w]; } s1[0]=a; s2[0]=c; }
  __syncthreads();
  float mean = s1[0] * (1.f/512.f);
  float var  = s2[0] * (1.f/512.f) - mean*mean;
  float rstd = rsqrtf(var + 1e-5f);
  __shared__ float P[256][17];
  float g[16];
  #pragma unroll
  for (int q = 0; q < 16; ++q) g[q] = 0.f;
  for (int i = tid; i < 512; i += 256){
    float v = (x[i]-mean)*rstd*s[i] + b[i];
    outb[(size_t)r*512 + i] = f2bf(v);
    const float* wrow = Wc + i*16;
    #pragma unroll
    for (int q = 0; q < 16; ++q) g[q] = fmaf(v, wrow[q], g[q]);
  }
  #pragma unroll
  for (int q = 0; q < 16; ++q) P[tid][q] = g[q];
  __syncthreads();
  {
    int q = tid >> 4, c = tid & 15;
    float sacc = 0.f;
    #pragma unroll
    for (int u = 0; u < 16; ++u) sacc += P[c*16 + u][q];
    sacc += __shfl_xor(sacc, 1); sacc += __shfl_xor(sacc, 2);
    sacc += __shfl_xor(sacc, 4); sacc += __shfl_xor(sacc, 8);
    if (c == 0) ipfp[r*16 + q] = sacc;
  }
}

// ---------------- 128x128-tile bf16 MFMA GEMM, multi-B: z selects (Bt, Cbf) ----------------
__global__ __launch_bounds__(256) void gemm_mfma128_multi(
    const unsigned short* __restrict__ A, int lda,
    const unsigned short* __restrict__ Bt0, const unsigned short* __restrict__ Bt1,
    const unsigned short* __restrict__ Bt2, int ldb,
    unsigned short* __restrict__ C0, unsigned short* __restrict__ C1,
    unsigned short* __restrict__ C2, int ldc, int K)
{
  const unsigned short* Bt = (blockIdx.z == 0) ? Bt0 : (blockIdx.z == 1) ? Bt1 : Bt2;
  unsigned short* Cbf      = (blockIdx.z == 0) ? C0  : (blockIdx.z == 1) ? C1  : C2;
  __shared__ __align__(16) unsigned short As[128][72];
  __shared__ __align__(16) unsigned short Bs[128][72];
  int row0 = blockIdx.y * 128, col0 = blockIdx.x * 128;
  int tid = threadIdx.x;
  int w = tid >> 6, l = tid & 63;
  int wr = (w >> 1) * 64, wc = (w & 1) * 64;
  int lr = l & 15, lk = l >> 4;
  f32x4 acc[4][4] = {};
  for (int k0 = 0; k0 < K; k0 += 64){
    #pragma unroll
    for (int u = 0; u < 4; ++u){
      int o = u*256 + tid, r = o >> 3, c = (o & 7) * 8;
      *(bf16x8*)&As[r][c] = *(const bf16x8*)(A  + (size_t)(row0 + r) * lda + k0 + c);
      *(bf16x8*)&Bs[r][c] = *(const bf16x8*)(Bt + (size_t)(col0 + r) * ldb + k0 + c);
    }
    __syncthreads();
    #pragma unroll
    for (int kk = 0; kk < 2; ++kk){
      bf16x8 af[4], bfr[4];
      #pragma unroll
      for (int i = 0; i < 4; ++i) af[i]  = *(const bf16x8*)&As[wr + i*16 + lr][kk*32 + lk*8];
      #pragma unroll
      for (int j = 0; j < 4; ++j) bfr[j] = *(const bf16x8*)&Bs[wc + j*16 + lr][kk*32 + lk*8];
      #pragma unroll
      for (int i = 0; i < 4; ++i)
        #pragma unroll
        for (int j = 0; j < 4; ++j)
          acc[i][j] = __builtin_amdgcn_mfma_f32_16x16x32_bf16(af[i], bfr[j], acc[i][j], 0, 0, 0);
    }
    __syncthreads();
  }
  #pragma unroll
  for (int i = 0; i < 4; ++i){
    #pragma unroll
    for (int j = 0; j < 4; ++j){
      int col = col0 + wc + j*16 + lr;
      #pragma unroll
      for (int r = 0; r < 4; ++r){
        int row = row0 + wr + i*16 + lk*4 + r;
        Cbf[(size_t)row*ldc + col] = f2bf(acc[i][j][r]);
      }
    }
  }
}

// ---------------- 64x64 bf16 MFMA GEMM (down-proj: fp32 out + skip) ----------------
__global__ __launch_bounds__(256) void gemm_mfma(
    const unsigned short* __restrict__ A, int lda,
    const unsigned short* __restrict__ Bt, int ldb,
    float* __restrict__ C, int ldc,
    unsigned short* __restrict__ Cbf,
    const float* __restrict__ skip, int ldskip,
    int K)
{
  __shared__ __align__(16) unsigned short As[64][72];
  __shared__ __align__(16) unsigned short Bs[64][72];
  int row0 = blockIdx.y * 64, col0 = blockIdx.x * 64;
  int tid = threadIdx.x;
  int w = tid >> 6, l = tid & 63;
  int wr = (w >> 1) * 32, wc = (w & 1) * 32;
  int lr = l & 15, lk = l >> 4;
  int r1 = tid >> 3, c1 = (tid & 7) * 8;
  int r2 = (tid + 256) >> 3, c2 = ((tid + 256) & 7) * 8;
  const unsigned short* a1 = A  + (size_t)(row0 + r1) * lda + c1;
  const unsigned short* a2 = A  + (size_t)(row0 + r2) * lda + c2;
  const unsigned short* b1 = Bt + (size_t)(col0 + r1) * ldb + c1;
  const unsigned short* b2 = Bt + (size_t)(col0 + r2) * ldb + c2;
  f32x4 acc00 = {0,0,0,0}, acc01 = {0,0,0,0}, acc10 = {0,0,0,0}, acc11 = {0,0,0,0};
  for (int k0 = 0; k0 < K; k0 += 64){
    *(bf16x8*)&As[r1][c1] = *(const bf16x8*)(a1 + k0);
    *(bf16x8*)&As[r2][c2] = *(const bf16x8*)(a2 + k0);
    *(bf16x8*)&Bs[r1][c1] = *(const bf16x8*)(b1 + k0);
    *(bf16x8*)&Bs[r2][c2] = *(const bf16x8*)(b2 + k0);
    __syncthreads();
    #pragma unroll
    for (int kk = 0; kk < 2; ++kk){
      bf16x8 a0 = *(const bf16x8*)&As[wr + lr][kk*32 + lk*8];
      bf16x8 a1f = *(const bf16x8*)&As[wr + 16 + lr][kk*32 + lk*8];
      bf16x8 b0 = *(const bf16x8*)&Bs[wc + lr][kk*32 + lk*8];
      bf16x8 b1f = *(const bf16x8*)&Bs[wc + 16 + lr][kk*32 + lk*8];
      acc00 = __builtin_amdgcn_mfma_f32_16x16x32_bf16(a0, b0, acc00, 0, 0, 0);
      acc01 = __builtin_amdgcn_mfma_f32_16x16x32_bf16(a0, b1f, acc01, 0, 0, 0);
      acc10 = __builtin_amdgcn_mfma_f32_16x16x32_bf16(a1f, b0, acc10, 0, 0, 0);
      acc11 = __builtin_amdgcn_mfma_f32_16x16x32_bf16(a1f, b1f, acc11, 0, 0, 0);
    }
    __syncthreads();
  }
  #pragma unroll
  for (int i = 0; i < 2; ++i){
    #pragma unroll
    for (int j = 0; j < 2; ++j){
      f32x4 a = (i == 0) ? ((j == 0) ? acc00 : acc01) : ((j == 0) ? acc10 : acc11);
      int col = col0 + wc + j*16 + lr;
      #pragma unroll
      for (int r = 0; r < 4; ++r){
        int row = row0 + wr + i*16 + lk*4 + r;
        float o = a[r];
        if (skip) o += skip[(size_t)row*ldskip + col];
        if (C)   C[(size_t)row*ldc + col] = o;
        if (Cbf) Cbf[(size_t)row*ldc + col] = f2bf(o);
      }
    }
  }
}

// ---------------- MFMA causal weighted attention (layer 0) + fused gate scan + epilogue ----------------
__global__ __launch_bounds__(256) void attn_l0_mfma(
    const unsigned short* __restrict__ q, const unsigned short* __restrict__ k,
    const unsigned short* __restrict__ v,
    const float* __restrict__ ipfp, const float* __restrict__ bi, const float* __restrict__ bfg,
    const unsigned short* __restrict__ xpb,
    const float* __restrict__ gn_s, const float* __restrict__ gn_b,
    unsigned short* __restrict__ gated)
{
  __shared__ __align__(16) char smem[48128];
  unsigned short (*Ks)[136] = (unsigned short(*)[136])smem;
  unsigned short (*Vt)[72]  = (unsigned short(*)[72])(smem + 17408);
  unsigned short (*Ps)[72]  = (unsigned short(*)[72])(smem + 35840);
  float* invden = (float*)(smem + 45056);
  float (*denL)[64] = (float(*)[64])(smem + 45568);
  float* alpha_full = (float*)(smem + 46080);
  float* Mt_full    = (float*)(smem + 47104);
  float (*numf)[140] = (float(*)[140])smem;

  int blk = blockIdx.x;
  int tt = blk & 3, h = (blk >> 2) & 7, b = blk >> 5;
  int t0 = tt * 64;
  int tid = threadIdx.x;
  int w = tid >> 6, l = tid & 63;
  int wr = (w >> 1) * 32;
  int wc = (w & 1) * 32;
  int wd = (w & 1) * 64;
  int lrm = l & 15, lk = l >> 4;
  size_t headoff = (size_t)h * 128;

  {
    #pragma unroll
    for (int u = 0; u < 4; ++u){
      int o = u*256 + tid, row = o >> 4, oct = o & 15;
      *(bf16x8*)&Ks[row][oct*8] =
        *(const bf16x8*)(q + (size_t)(b*256 + t0 + row)*1024 + headoff + oct*8);
    }
    if (tid < 64){
      int lane = tid;
      float bih = bi[h], bfh = bfg[h];
      float lf[4], ip4[4];
      #pragma unroll
      for (int u = 0; u < 4; ++u){
        int r = b*256 + lane*4 + u;
        ip4[u] = ipfp[r*16 + h] + bih;
        lf[u]  = logsig_f(ipfp[r*16 + 8 + h] + bfh);
      }
      float c0 = lf[0], c1 = c0+lf[1], c2 = c1+lf[2], c3 = c2+lf[3];
      float tot = c3, pre = tot;
      #pragma unroll
      for (int o = 1; o < 64; o <<= 1){ float vv = __shfl_up(pre, o); if (lane >= o) pre += vv; }
      float excl = pre - tot;
      float al[4] = { ip4[0]-(excl+c0), ip4[1]-(excl+c1), ip4[2]-(excl+c2), ip4[3]-(excl+c3) };
      float lm[4];
      lm[0]=al[0]; lm[1]=fmaxf(lm[0],al[1]); lm[2]=fmaxf(lm[1],al[2]); lm[3]=fmaxf(lm[2],al[3]);
      float pm = lm[3];
      #pragma unroll
      for (int o = 1; o < 64; o <<= 1){ float vv = __shfl_up(pm, o); if (lane >= o) pm = fmaxf(pm, vv); }
      float pmexcl = __shfl_up(pm, 1);
      if (lane == 0) pmexcl = -3.4e38f;
      #pragma unroll
      for (int u = 0; u < 4; ++u){
        alpha_full[lane*4+u] = al[u];
        Mt_full[lane*4+u] = fmaxf(0.f, fmaxf(pmexcl, lm[u]));
      }
    }
    if (tid < 128) ((float*)denL)[tid] = 0.f;
  }
  __syncthreads();
  bf16x8 aq[2][4];
  #pragma unroll
  for (int i = 0; i < 2; ++i)
    #pragma unroll
    for (int kk = 0; kk < 4; ++kk)
      aq[i][kk] = *(const bf16x8*)&Ks[wr + i*16 + lrm][kk*32 + lk*8];
  __syncthreads();

  f32x4 pacc[2][4] = {};
  int ntile = tt + 1;

  for (int it = 0; it < ntile; ++it){
    int s0 = it * 64;
    #pragma unroll
    for (int u = 0; u < 4; ++u){
      int o = u*256 + tid, row = o >> 4, oct = o & 15;
      *(bf16x8*)&Ks[row][oct*8] =
        *(const bf16x8*)(k + (size_t)(b*256 + s0 + row)*1024 + headoff + oct*8);
    }
    #pragma unroll
    for (int u = 0; u < 2; ++u){
      int task = u*256 + tid;
      int sp = task & 31, oct = task >> 5;
      const unsigned short* vp = v + (size_t)(b*256 + s0 + sp*2)*1024 + headoff + oct*8;
      bf16x8 r0 = *(const bf16x8*)vp;
      bf16x8 r1 = *(const bf16x8*)(vp + 1024);
      #pragma unroll
      for (int j = 0; j < 8; ++j){
        unsigned lo = (unsigned short)r0[j];
        unsigned hi = (unsigned short)r1[j];
        *(unsigned*)&Vt[oct*8 + j][sp*2] = lo | (hi << 16);
      }
    }
    __syncthreads();

    f32x4 sacc[2][2] = {};
    #pragma unroll
    for (int kk = 0; kk < 4; ++kk){
      bf16x8 b0 = *(const bf16x8*)&Ks[wc + lrm][kk*32 + lk*8];
      bf16x8 b1 = *(const bf16x8*)&Ks[wc + 16 + lrm][kk*32 + lk*8];
      sacc[0][0] = __builtin_amdgcn_mfma_f32_16x16x32_bf16(aq[0][kk], b0, sacc[0][0], 0, 0, 0);
      sacc[0][1] = __builtin_amdgcn_mfma_f32_16x16x32_bf16(aq[0][kk], b1, sacc[0][1], 0, 0, 0);
      sacc[1][0] = __builtin_amdgcn_mfma_f32_16x16x32_bf16(aq[1][kk], b0, sacc[1][0], 0, 0, 0);
      sacc[1][1] = __builtin_amdgcn_mfma_f32_16x16x32_bf16(aq[1][kk], b1, sacc[1][1], 0, 0, 0);
    }

    bool diag = (it == ntile - 1);
    float av0 = alpha_full[s0 + wc + lrm];
    float av1 = alpha_full[s0 + wc + 16 + lrm];
    #pragma unroll
    for (int i = 0; i < 2; ++i){
      #pragma unroll
      for (int r = 0; r < 4; ++r){
        int tl = wr + i*16 + lk*4 + r;
        float mt = Mt_full[t0 + tl];
        float p0 = __expf(av0 - mt) * sacc[i][0][r];
        float p1 = __expf(av1 - mt) * sacc[i][1][r];
        if (diag){
          if (wc + lrm      > tl) p0 = 0.f;
          if (wc + 16 + lrm > tl) p1 = 0.f;
        }
        Ps[tl][wc + lrm]      = f2bf(p0);
        Ps[tl][wc + 16 + lrm] = f2bf(p1);
        float dv = p0 + p1;
        dv += __shfl_xor(dv, 1); dv += __shfl_xor(dv, 2);
        dv += __shfl_xor(dv, 4); dv += __shfl_xor(dv, 8);
        if (lrm == 0) denL[w & 1][tl] += dv;
      }
    }
    __syncthreads();

    #pragma unroll
    for (int ks = 0; ks < 2; ++ks){
      bf16x8 pa0 = *(const bf16x8*)&Ps[wr + lrm][ks*32 + lk*8];
      bf16x8 pa1 = *(const bf16x8*)&Ps[wr + 16 + lrm][ks*32 + lk*8];
      #pragma unroll
      for (int jd = 0; jd < 4; ++jd){
        bf16x8 vb8 = *(const bf16x8*)&Vt[wd + jd*16 + lrm][ks*32 + lk*8];
        pacc[0][jd] = __builtin_amdgcn_mfma_f32_16x16x32_bf16(pa0, vb8, pacc[0][jd], 0, 0, 0);
        pacc[1][jd] = __builtin_amdgcn_mfma_f32_16x16x32_bf16(pa1, vb8, pacc[1][jd], 0, 0, 0);
      }
    }
    __syncthreads();
  }

  #pragma unroll
  for (int i = 0; i < 2; ++i)
    #pragma unroll
    for (int jd = 0; jd < 4; ++jd)
      #pragma unroll
      for (int r = 0; r < 4; ++r)
        numf[wr + i*16 + lk*4 + r][wd + jd*16 + lrm] = pacc[i][jd][r];
  if (tid < 64){
    float s = denL[0][tid] + denL[1][tid];
    invden[tid] = 1.0f / fmaxf(fabsf(s), 1.0f);
  }
  __syncthreads();

  {
    int row = tid >> 2, qq = tid & 3;
    float inv = invden[row];
    const float* nr = &numf[row][qq*32];
    float xs[32];
    float sum = 0.f, sq = 0.f;
    #pragma unroll
    for (int j = 0; j < 8; ++j){
      float4 t4 = *(const float4*)(nr + j*4);
      float v0 = t4.x*inv, v1 = t4.y*inv, v2 = t4.z*inv, v3 = t4.w*inv;
      xs[j*4+0] = v0; xs[j*4+1] = v1; xs[j*4+2] = v2; xs[j*4+3] = v3;
      sum += v0+v1+v2+v3;
      sq  += v0*v0+v1*v1+v2*v2+v3*v3;
    }
    sum += __shfl_xor(sum, 1); sq += __shfl_xor(sq, 1);
    sum += __shfl_xor(sum, 2); sq += __shfl_xor(sq, 2);
    float mean = sum * (1.f/128.f);
    float var  = sq  * (1.f/128.f) - mean*mean;
    float rstd = rsqrtf(var + 1e-5f);
    int rr = b*256 + t0 + row;
    const unsigned short* zp = xpb + (size_t)rr*2048 + 1024 + headoff + qq*32;
    const float* gsP = gn_s + headoff + qq*32;
    const float* gbP = gn_b + headoff + qq*32;
    unsigned short* op = gated + (size_t)rr*1024 + headoff + qq*32;
    #pragma unroll
    for (int j8 = 0; j8 < 4; ++j8){
      bf16x8 zv = *(const bf16x8*)(zp + j8*8);
      bf16x8 ov;
      #pragma unroll
      for (int j = 0; j < 8; ++j){
        int jj = j8*8 + j;
        float valn = (xs[jj]-mean)*rstd*gsP[jj] + gbP[jj];
        ov[j] = (short)f2bf(valn * silu_f(bf2f((unsigned short)zv[j])));
      }
      *(bf16x8*)(op + j8*8) = ov;
    }
  }
}

// ---------------- layer 1 q at last step: split-K GEMV (fp32 Wq, coalesced) ----------------
__global__ void qlast_split(const unsigned short* __restrict__ xpb, const float* __restrict__ Wq1,
                            float* __restrict__ part)
{
  int jt = blockIdx.x, ks = blockIdx.y;      // (4, 32)
  int j = jt*256 + threadIdx.x;
  __shared__ float xs[4][32];
  int t = threadIdx.x;
  if (t < 128){ int b = t >> 5, kk = t & 31; xs[b][kk] = bf2f(xpb[(size_t)(b*256+255)*2048 + ks*32 + kk]); }
  __syncthreads();
  float a0=0.f,a1=0.f,a2=0.f,a3=0.f;
  #pragma unroll 8
  for (int kk = 0; kk < 32; ++kk){
    float wv = Wq1[(size_t)(ks*32+kk)*1024 + j];
    a0 = fmaf(xs[0][kk], wv, a0);
    a1 = fmaf(xs[1][kk], wv, a1);
    a2 = fmaf(xs[2][kk], wv, a2);
    a3 = fmaf(xs[3][kk], wv, a3);
  }
  part[((size_t)ks*4 + 0)*1024 + j] = a0;
  part[((size_t)ks*4 + 1)*1024 + j] = a1;
  part[((size_t)ks*4 + 2)*1024 + j] = a2;
  part[((size_t)ks*4 + 3)*1024 + j] = a3;
}

// ---------------- layer 1 last-step attention: split over s-chunks (q-reduce + gate scan fused) ----------------
__global__ __launch_bounds__(256) void attn_l1_split(
    const float* __restrict__ qpart, const unsigned short* __restrict__ k1,
    const unsigned short* __restrict__ v1,
    const float* __restrict__ ipfp, const float* __restrict__ bi, const float* __restrict__ bfg,
    float* __restrict__ pnum, float* __restrict__ pden)
{
  int sc = blockIdx.x, bh = blockIdx.y;      // (8, 32)
  int b = bh >> 3, h = bh & 7;
  int s0 = sc * 32;
  int tid = threadIdx.x;
  __shared__ float qsh[128];
  __shared__ float alpha256[256];
  __shared__ float mt255s;
  __shared__ float sred[32][9];
  __shared__ float as[32];
  __shared__ float nred[2][128];
  if (tid < 128){
    float s = 0.f;
    #pragma unroll 8
    for (int ks = 0; ks < 32; ++ks) s += qpart[((size_t)ks*4 + b)*1024 + h*128 + tid];
    qsh[tid] = s;
  }
  if (tid >= 128 && tid < 192){
    int lane = tid - 128;
    float bih = bi[h], bfh = bfg[h];
    float lf[4], ip4[4];
    #pragma unroll
    for (int u = 0; u < 4; ++u){
      int r = b*256 + lane*4 + u;
      ip4[u] = ipfp[r*16 + h] + bih;
      lf[u]  = logsig_f(ipfp[r*16 + 8 + h] + bfh);
    }
    float c0 = lf[0], c1 = c0+lf[1], c2 = c1+lf[2], c3 = c2+lf[3];
    float tot = c3, pre = tot;
    #pragma unroll
    for (int o = 1; o < 64; o <<= 1){ float vv = __shfl_up(pre, o); if (lane >= o) pre += vv; }
    float excl = pre - tot;
    float al[4] = { ip4[0]-(excl+c0), ip4[1]-(excl+c1), ip4[2]-(excl+c2), ip4[3]-(excl+c3) };
    #pragma unroll
    for (int u = 0; u < 4; ++u) alpha256[lane*4+u] = al[u];
    float mx = fmaxf(fmaxf(al[0],al[1]), fmaxf(al[2],al[3]));
    #pragma unroll
    for (int o = 32; o > 0; o >>= 1) mx = fmaxf(mx, __shfl_xor(mx, o));
    if (lane == 0) mt255s = fmaxf(0.f, mx);
  }
  __syncthreads();
  {
    int sl = tid & 31, dc = tid >> 5;
    const unsigned short* kp = k1 + (size_t)(b*256 + s0 + sl)*1024 + h*128 + dc*16;
    float p = 0.f;
    #pragma unroll
    for (int u = 0; u < 16; u += 8){
      bf16x8 kv = *(const bf16x8*)(kp + u);
      #pragma unroll
      for (int e = 0; e < 8; ++e) p = fmaf(qsh[dc*16+u+e], bf2f((unsigned short)kv[e]), p);
    }
    sred[sl][dc] = p;
  }
  __syncthreads();
  if (tid < 32){
    float sum = 0.f;
    #pragma unroll
    for (int dc = 0; dc < 8; ++dc) sum += sred[tid][dc];
    float w = __expf(alpha256[s0 + tid] - mt255s);
    as[tid] = w * sum;
  }
  __syncthreads();
  {
    int d = tid & 127, sg = tid >> 7;
    const unsigned short* vp = v1 + (size_t)(b*256 + s0 + sg*16)*1024 + h*128 + d;
    float np = 0.f;
    #pragma unroll
    for (int u = 0; u < 16; ++u) np = fmaf(as[sg*16 + u], bf2f(vp[(size_t)u*1024]), np);
    nred[sg][d] = np;
  }
  __syncthreads();
  if (tid < 128) pnum[((size_t)bh*8 + sc)*128 + tid] = nred[0][tid] + nred[1][tid];
  if (tid == 128){
    float dsum = 0.f;
    #pragma unroll
    for (int u = 0; u < 32; ++u) dsum += as[u];
    pden[bh*8 + sc] = dsum;
  }
}

// ---------------- layer 1 finalize: combine partials + LN + affine + SiLU gate ----------------
__global__ __launch_bounds__(128) void attn_l1_fin(
    const float* __restrict__ pnum, const float* __restrict__ pden,
    const unsigned short* __restrict__ xpb,
    const float* __restrict__ gn_s, const float* __restrict__ gn_b,
    float* __restrict__ gated1)
{
  int bh = blockIdx.x; int b = bh >> 3, h = bh & 7;
  int tid = threadIdx.x;
  __shared__ float hh[128];
  __shared__ float dsh, msh, rsh;
  float nsum = 0.f;
  #pragma unroll
  for (int sc = 0; sc < 8; ++sc) nsum += pnum[((size_t)bh*8 + sc)*128 + tid];
  if (tid == 0){
    float d = 0.f;
    #pragma unroll
    for (int sc = 0; sc < 8; ++sc) d += pden[bh*8 + sc];
    dsh = fmaxf(fabsf(d), 1.0f);
  }
  __syncthreads();
  float hv = nsum / dsh;
  hh[tid] = hv;
  __syncthreads();
  if (tid < 64){
    float a = hh[tid], c = hh[tid + 64];
    float s1 = a + c, s2v = a*a + c*c;
    #pragma unroll
    for (int o = 32; o > 0; o >>= 1){ s1 += __shfl_down(s1, o); s2v += __shfl_down(s2v, o); }
    if (tid == 0){
      float mean = s1*(1.f/128.f);
      float var  = s2v*(1.f/128.f) - mean*mean;
      msh = mean; rsh = rsqrtf(var + 1e-5f);
    }
  }
  __syncthreads();
  {
    int i = h*128 + tid;
    float valn = (hv - msh)*rsh*gn_s[i] + gn_b[i];
    float z = bf2f(xpb[(size_t)(b*256 + 255)*2048 + 1024 + i]);
    gated1[b*1024 + i] = valn * silu_f(z);
  }
}

// ---------------- last-step down proj: split-K (fp32 Wd, coalesced) ----------------
__global__ void dl_split(const float* __restrict__ gated1, const float* __restrict__ Wd,
                         float* __restrict__ part)
{
  int jt = blockIdx.x, ks = blockIdx.y;      // (2, 32)
  int j = jt*256 + threadIdx.x;
  __shared__ float xs[4][32];
  int t = threadIdx.x;
  if (t < 128){ int b = t >> 5, kk = t & 31; xs[b][kk] = gated1[b*1024 + ks*32 + kk]; }
  __syncthreads();
  float a0=0.f,a1=0.f,a2=0.f,a3=0.f;
  #pragma unroll 8
  for (int kk = 0; kk < 32; ++kk){
    float wv = Wd[(size_t)(ks*32+kk)*512 + j];
    a0 = fmaf(xs[0][kk], wv, a0);
    a1 = fmaf(xs[1][kk], wv, a1);
    a2 = fmaf(xs[2][kk], wv, a2);
    a3 = fmaf(xs[3][kk], wv, a3);
  }
  part[((size_t)ks*4 + 0)*512 + j] = a0;
  part[((size_t)ks*4 + 1)*512 + j] = a1;
  part[((size_t)ks*4 + 2)*512 + j] = a2;
  part[((size_t)ks*4 + 3)*512 + j] = a3;
}

// ---------------- last-step: down-proj partials + skip + final LN + pi head (fused) ----------------
__global__ __launch_bounds__(256) void dl_fin(
    const float* __restrict__ part, const float* __restrict__ h0,
    const float* __restrict__ fln_s, const float* __restrict__ fln_b,
    const float* __restrict__ W_pi, const float* __restrict__ b_pi,
    float* __restrict__ lastb, float* __restrict__ out)
{
  int b = blockIdx.x;     // 4 blocks
  int tid = threadIdx.x;
  __shared__ float ls[512];
  __shared__ float pred[8][33];
  __shared__ float s1[4], s2[4];
  float v[2];
  #pragma unroll
  for (int u = 0; u < 2; ++u){
    int jj = tid*2 + u;
    float s = 0.f;
    #pragma unroll 8
    for (int ks = 0; ks < 32; ++ks) s += part[((size_t)ks*4 + b)*512 + jj];
    v[u] = h0[(size_t)(b*256 + 255)*512 + jj] + s;
  }
  float lsum = v[0] + v[1], lsq = v[0]*v[0] + v[1]*v[1];
  #pragma unroll
  for (int o = 32; o > 0; o >>= 1){ lsum += __shfl_down(lsum, o); lsq += __shfl_down(lsq, o); }
  int wid = tid >> 6, lane = tid & 63;
  if (lane == 0){ s1[wid] = lsum; s2[wid] = lsq; }
  __syncthreads();
  if (tid == 0){ float a=0.f,c=0.f; for (int w2=0; w2<4; ++w2){ a+=s1[w2]; c+=s2[w2]; } s1[0]=a; s2[0]=c; }
  __syncthreads();
  float mean = s1[0] * (1.f/512.f);
  float var  = s2[0] * (1.f/512.f) - mean*mean;
  float rstd = rsqrtf(var + 1e-5f);
  #pragma unroll
  for (int u = 0; u < 2; ++u){
    int jj = tid*2 + u;
    float lv = (v[u]-mean)*rstd*fln_s[jj] + fln_b[jj];
    lastb[b*512 + jj] = lv;
    ls[jj] = lv;
  }
  __syncthreads();
  {
    int o = tid & 31, pt = tid >> 5;
    float pa = 0.f;
    #pragma unroll 8
    for (int u = 0; u < 64; ++u){ int i = pt*64 + u; pa = fmaf(ls[i], W_pi[i*32 + o], pa); }
    pred[pt][o] = pa;
  }
  __syncthreads();
  if (tid < 32){
    float acc = b_pi[tid];
    #pragma unroll
    for (int pt = 0; pt < 8; ++pt) acc += pred[pt][tid];
    float m = acc;
    #pragma unroll
    for (int o2 = 16; o2 > 0; o2 >>= 1) m = fmaxf(m, __shfl_xor(m, o2));
    float e = __expf(acc - m);
    float ss = e;
    #pragma unroll
    for (int o2 = 16; o2 > 0; o2 >>= 1) ss += __shfl_xor(ss, o2);
    out[b*32 + tid] = e / ss;
  }
}

// ---------------- MDN mu/sigma heads: split-K ----------------
__global__ void ms_split(const float* __restrict__ last,
                         const float* __restrict__ W_mu, const float* __restrict__ W_sig,
                         float* __restrict__ part)
{
  int jt = blockIdx.x, ks = blockIdx.y, mat = blockIdx.z;  // (8, 8, 2)
  int j = jt*256 + threadIdx.x;
  const float* W = mat ? W_sig : W_mu;
  __shared__ float xs[4][64];
  int t = threadIdx.x;
  { int b = t >> 6, kk = t & 63; xs[b][kk] = last[b*512 + ks*64 + kk]; }
  __syncthreads();
  float a0=0.f,a1=0.f,a2=0.f,a3=0.f;
  #pragma unroll 8
  for (int kk = 0; kk < 64; ++kk){
    float wv = W[(size_t)(ks*64+kk)*2048 + j];
    a0 = fmaf(xs[0][kk], wv, a0);
    a1 = fmaf(xs[1][kk], wv, a1);
    a2 = fmaf(xs[2][kk], wv, a2);
    a3 = fmaf(xs[3][kk], wv, a3);
  }
  size_t base = ((size_t)(mat*8 + ks)*4);
  part[(base + 0)*2048 + j] = a0;
  part[(base + 1)*2048 + j] = a1;
  part[(base + 2)*2048 + j] = a2;
  part[(base + 3)*2048 + j] = a3;
}

__global__ void ms_reduce(const float* __restrict__ part,
                          const float* __restrict__ b_mu, const float* __restrict__ b_sig,
                          float* __restrict__ out)
{
  int j = blockIdx.x*256 + threadIdx.x;      // 2048
  int b = blockIdx.y, mat = blockIdx.z;
  float s = mat ? b_sig[j] : b_mu[j];
  for (int ks = 0; ks < 8; ++ks) s += part[((size_t)(mat*8 + ks)*4 + b)*2048 + j];
  out[128 + mat*8192 + b*2048 + j] = mat ? softplus_f(s) : s;
}

// ---------------- launch ----------------
extern "C" void kernel_launch(void* const* d_in, const int* in_sizes, int n_in,
                              void* d_out, int out_size, void* d_ws, size_t ws_size,
                              hipStream_t stream)
{
  const float* x      = (const float*)d_in[0];
  const float* ln_s   = (const float*)d_in[1];
  const float* ln_b   = (const float*)d_in[2];
  const float* W_proj = (const float*)d_in[3];
  const float* Wq     = (const float*)d_in[4];
  const float* Wk     = (const float*)d_in[5];
  const float* Wv     = (const float*)d_in[6];
  const float* Wi     = (const float*)d_in[7];
  const float* bi     = (const float*)d_in[8];
  const float* Wf     = (const float*)d_in[9];
  const float* bf     = (const float*)d_in[10];
  const float* gn_s   = (const float*)d_in[11];
  const float* gn_b   = (const float*)d_in[12];
  const float* W_down = (const float*)d_in[13];
  const float* fln_s  = (const float*)d_in[14];
  const float* fln_b  = (const float*)d_in[15];
  const float* W_pi   = (const float*)d_in[16];
  const float* b_pi   = (const float*)d_in[17];
  const float* W_mu   = (const float*)d_in[18];
  const float* b_mu   = (const float*)d_in[19];
  const float* W_sig  = (const float*)d_in[20];
  const float* b_sig  = (const float*)d_in[21];
  float* out = (float*)d_out;

  char* p = (char*)d_ws;
  unsigned short* projT0 = (unsigned short*)p; p += (size_t)2048*512*2;
  unsigned short* projT1 = (unsigned short*)p; p += (size_t)2048*512*2;
  unsigned short* qT0    = (unsigned short*)p; p += (size_t)1024*1024*2;
  unsigned short* kT0    = (unsigned short*)p; p += (size_t)1024*1024*2;
  unsigned short* kT1    = (unsigned short*)p; p += (size_t)1024*1024*2;
  unsigned short* vT0    = (unsigned short*)p; p += (size_t)1024*1024*2;
  unsigned short* vT1    = (unsigned short*)p; p += (size_t)1024*1024*2;
  unsigned short* dT0    = (unsigned short*)p; p += (size_t)512*1024*2;
  float* Wc              = (float*)p;          p += (size_t)2*512*16*4;
  unsigned short* xnb    = (unsigned short*)p; p += (size_t)1024*512*2;
  unsigned short* xpb    = (unsigned short*)p; p += (size_t)1024*2048*2;
  unsigned short* qbb    = (unsigned short*)p; p += (size_t)1024*1024*2;
  unsigned short* kbb    = (unsigned short*)p; p += (size_t)1024*1024*2;
  unsigned short* vbb    = (unsigned short*)p; p += (size_t)1024*1024*2;
  unsigned short* gatedb = (unsigned short*)p; p += (size_t)1024*1024*2;
  float* h0     = (float*)p; p += (size_t)1024*512*4;
  float* ipfp   = (float*)p; p += (size_t)16384*4;
  float* gated1 = (float*)p; p += (size_t)4096*4;
  float* lastb  = (float*)p; p += (size_t)2048*4;
  float* qpart  = (float*)p; p += (size_t)32*4096*4;
  float* dpart  = (float*)p; p += (size_t)32*4*512*4;
  float* pnum   = (float*)p; p += (size_t)32*8*128*4;
  float* pden   = (float*)p; p += (size_t)32*8*4;
  float* mspart = (float*)p; p += (size_t)16*4*2048*4;

  const float* ln_s1 = ln_s + 512;
  const float* ln_b1 = ln_b + 512;
  const float* gn_s1 = gn_s + 1024;
  const float* gn_b1 = gn_b + 1024;
  const float* Wq1   = Wq + 1024*1024;
  const float* Wd1   = W_down + 1024*512;

  dim3 blk256(256);

  // weight prep (960 transpose tiles + 256 compose blocks)
  wprep<<<1216, blk256, 0, stream>>>(W_proj, Wq, Wk, Wv, W_down, Wi, Wf,
      projT0, projT1, qT0, kT0, kT1, vT0, vT1, dT0, Wc);

  // ---------- layer 0 ----------
  ln_gates<<<1024, blk256, 0, stream>>>(x, xnb, ln_s, ln_b, Wc, ipfp);
  gemm_mfma128_multi<<<dim3(16,8,1), blk256, 0, stream>>>(xnb, 512, projT0, projT0, projT0, 512, xpb, xpb, xpb, 2048, 512);
  gemm_mfma128_multi<<<dim3(8,8,3), blk256, 0, stream>>>(xpb, 2048, qT0, kT0, vT0, 1024, qbb, kbb, vbb, 1024, 1024);
  attn_l0_mfma<<<128, blk256, 0, stream>>>(qbb, kbb, vbb, ipfp, bi, bf, xpb, gn_s, gn_b, gatedb);
  gemm_mfma<<<dim3(8,16), blk256, 0, stream>>>(gatedb, 1024, dT0, 1024, h0, 512, nullptr, x, 512, 1024);

  // ---------- layer 1 ----------
  ln_gates<<<1024, blk256, 0, stream>>>(h0, xnb, ln_s1, ln_b1, Wc + 512*16, ipfp);
  gemm_mfma128_multi<<<dim3(16,8,1), blk256, 0, stream>>>(xnb, 512, projT1, projT1, projT1, 512, xpb, xpb, xpb, 2048, 512);
  gemm_mfma128_multi<<<dim3(8,8,2), blk256, 0, stream>>>(xpb, 2048, kT1, vT1, vT1, 1024, kbb, vbb, vbb, 1024, 1024);
  qlast_split<<<dim3(4,32), blk256, 0, stream>>>(xpb, Wq1, qpart);
  attn_l1_split<<<dim3(8,32), blk256, 0, stream>>>(qpart, kbb, vbb, ipfp, bi + 8, bf + 8, pnum, pden);
  attn_l1_fin<<<32, 128, 0, stream>>>(pnum, pden, xpb, gn_s1, gn_b1, gated1);
  dl_split<<<dim3(2,32), blk256, 0, stream>>>(gated1, Wd1, dpart);
  dl_fin<<<4, blk256, 0, stream>>>(dpart, h0, fln_s, fln_b, W_pi, b_pi, lastb, out);

  // ---------- final head ----------
  ms_split<<<dim3(8,8,2), blk256, 0, stream>>>(lastb, W_mu, W_sig, mspart);
  ms_reduce<<<dim3(8,4,2), blk256, 0, stream>>>(mspart, b_mu, b_sig, out);
}